// Round 13
// baseline (749.248 us; speedup 1.0000x reference)
//
#include <hip/hip_runtime.h>
#include <hip/hip_bf16.h>

typedef __attribute__((ext_vector_type(8))) short bf16x8;
typedef __attribute__((ext_vector_type(4))) short bf16x4;
typedef __attribute__((ext_vector_type(4))) float f32x4;
typedef __attribute__((ext_vector_type(2))) float f32x2;

#define NPEDS 65536
#define SEQ 12
#define HD 128
#define ED 64
#define MBLK 128  // peds per block: 8 waves x ONE 16-ped tile each
#define WHH_FRAGS 128
#define WEFF_FRAGS 132  // 128 gate frags + 4 w_hp frags
#define NFRAGS (WHH_FRAGS + WEFF_FRAGS)
#define L2E 1.44269504088896340736f
#define NEG2L (-2.88539008177792681472f)
// float tail after frags: beff[512], b0eff[512], w2[1024]

__device__ __forceinline__ short f2bf(float x) {
  __hip_bfloat16 b = __float2bfloat16(x);  // RNE
  return __builtin_bit_cast(short, b);
}
__device__ __forceinline__ float exp2_(float x) {
#if __has_builtin(__builtin_amdgcn_exp2f)
  return __builtin_amdgcn_exp2f(x);
#else
  return exp2f(x);
#endif
}

// Gate rows PRE-SCALED by log2e (2*log2e for gate g; torch order i,f,g,o):
// sigm(x)=rcp(1+exp2(-y)); tanh(g)=(2-R)/R, R=1+exp2(-yg).
// wsB layout (shorts):
//  [0, 128*512):         step-0 frags (w_hh, scaled), frag = (c*4+g)*4+kt
//  [128*512, 256*512):   W_eff gate frags (scaled),   frag = (c*4+g)*4+kt
//  [256*512, 260*512):   w_hp rel frags (UNscaled),   frag = kt
//  float tail fl[]: fl[0:512) beff, fl[512:1024) b0eff, fl[1024:2048) w2[n][2]
__global__ void prep_kernel(const float* __restrict__ w_ih,
                            const float* __restrict__ w_hh,
                            const float* __restrict__ w_se,
                            const float* __restrict__ w_hp,
                            const float* __restrict__ b_ih,
                            const float* __restrict__ b_hh,
                            const float* __restrict__ b_se,
                            const float* __restrict__ b_hp,
                            short* __restrict__ wsB, float* __restrict__ fl) {
  int t = blockIdx.x * 256 + threadIdx.x;
  if (t < WHH_FRAGS * 64) {
    int frag = t >> 6, l = t & 63;
    int cc = frag >> 4, g = (frag >> 2) & 3, kt = frag & 3;
    float fac = (g == 2) ? 2.0f * L2E : L2E;
    int n = g * HD + cc * 16 + (l & 15);
    bf16x8 v;
#pragma unroll
    for (int e = 0; e < 8; ++e) {
      int k = kt * 32 + ((l >> 4) << 2) + (e & 3) + ((e >> 2) << 4);
      v[e] = f2bf(w_hh[n * HD + k] * fac);
    }
    *(bf16x8*)(wsB + (size_t)frag * 512 + l * 8) = v;
  } else if (t < NFRAGS * 64) {
    int u = t - WHH_FRAGS * 64;
    int frag = u >> 6, l = u & 63;
    int llo = l & 15;
    int ks[8];
#pragma unroll
    for (int e = 0; e < 8; ++e)
      ks[e] = (frag & 3) * 32 + ((l >> 4) << 2) + (e & 3) + ((e >> 2) << 4);
    float acc[8];
    if (frag < 128) {
      int cc = frag >> 4, g = (frag >> 2) & 3;
      float fac = (g == 2) ? 2.0f * L2E : L2E;
      int n = g * HD + cc * 16 + llo;
#pragma unroll
      for (int e = 0; e < 8; ++e) acc[e] = w_hh[n * HD + ks[e]];
      for (int j = 0; j < ED; ++j) {
        float wij = w_ih[n * ED + j];
        float se0 = w_se[2 * j], se1 = w_se[2 * j + 1];
#pragma unroll
        for (int e = 0; e < 8; ++e)
          acc[e] += wij * (se0 * w_hp[ks[e]] + se1 * w_hp[HD + ks[e]]);
      }
#pragma unroll
      for (int e = 0; e < 8; ++e) acc[e] *= fac;
    } else {
#pragma unroll
      for (int e = 0; e < 8; ++e)
        acc[e] = (llo < 2) ? w_hp[llo * HD + ks[e]] : 0.f;
    }
    bf16x8 v;
#pragma unroll
    for (int e = 0; e < 8; ++e) v[e] = f2bf(acc[e]);
    *(bf16x8*)(wsB + (size_t)(WHH_FRAGS + frag) * 512 + l * 8) = v;
  } else if (t < NFRAGS * 64 + 512) {
    int n = t - NFRAGS * 64;
    float fac = ((n >> 7) == 2) ? 2.0f * L2E : L2E;
    float b = b_ih[n] + b_hh[n];
    float s0 = 0.f, w20 = 0.f, w21 = 0.f;
    for (int j = 0; j < ED; ++j) {
      float wij = w_ih[n * ED + j];
      s0 += wij * b_se[j];
      w20 += wij * w_se[2 * j];
      w21 += wij * w_se[2 * j + 1];
    }
    fl[n] = fac * (b + s0 + w20 * b_hp[0] + w21 * b_hp[1]);  // beff (s>=1)
    fl[512 + n] = fac * (b + s0);                            // b0eff (step 0)
    fl[1024 + 2 * n] = fac * w20;  // w2 = w_ih @ w_se (scaled)
    fl[1024 + 2 * n + 1] = fac * w21;
  }
}

// BARRIER-FREE RECURRENCE, single ped-tile per wave (R11's architecture --
// which PASSED refcheck, proving the in-register C->B repack -- with HALF
// the register state, which is what sank R11 into scratch).
// Each wave owns 16 peds and computes all 512 gate cols; weights live in
// LDS (one shared 128 KB copy), h/c live in registers. The swapped-operand
// C-layout (ped=llo, col=lhi*4+r) IS the next step's B-fragment in the same
// lane -> no LDS h-exchange, no __syncthreads in the 12-step loop.
// Live set ~165 peak (Bh 16 + BhN 16 + creg 32 + acc 16 + in-flight weight
// reads) vs cap 256 at launch_bounds(512,2) -- wide no-spill margin.
__global__ __launch_bounds__(512, 2) void lstm_kernel(
    const float* __restrict__ lpr, const float* __restrict__ h0,
    const float* __restrict__ c0, const float* __restrict__ b_hp,
    const short* __restrict__ wsB, const float* __restrict__ fl,
    float* __restrict__ out) {
  __shared__ __align__(16) short s_w[WHH_FRAGS * 512];  // 128 KB weight frags
  __shared__ __align__(16) short s_whp[4 * 512];        // 4 KB w_hp frags
  __shared__ __align__(16) float s_beff[512];           // 2 KB folded bias

  const int tid = threadIdx.x;
  const int l = tid & 63;
  const int lhi = l >> 4;
  const int llo = l & 15;
  const int pbase = blockIdx.x * MBLK + (tid >> 6) * 16;
  const int ped = pbase + llo;  // this lane's ped

  // stage w_hh frags (131072 B) for step 0
  {
    const f32x4* src = (const f32x4*)wsB;
    f32x4* dst = (f32x4*)s_w;
#pragma unroll
    for (int i = 0; i < 16; ++i) dst[i * 512 + tid] = src[i * 512 + tid];
  }
  if (tid < 256)
    ((f32x4*)s_whp)[tid] =
        ((const f32x4*)(wsB + (size_t)(WHH_FRAGS + 128) * 512))[tid];
  s_beff[tid] = fl[tid];

  // c-state in registers: creg[c][r] = c0[ped][c*16 + lhi*4 + r]
  f32x4 creg[8];
#pragma unroll
  for (int c = 0; c < 8; ++c)
    creg[c] = *(const f32x4*)&c0[(size_t)ped * HD + c * 16 + lhi * 4];

  // h-state as B-fragments: k = kt*32 + lhi*4 + (e&3) + 16*(e>>2)
  bf16x8 Bh[4];
#pragma unroll
  for (int kt = 0; kt < 4; ++kt) {
    const float* hp = &h0[(size_t)ped * HD + kt * 32 + lhi * 4];
    f32x4 lo = *(const f32x4*)hp;
    f32x4 hi = *(const f32x4*)(hp + 16);
    bf16x4 a, b;
    a[0] = f2bf(lo[0]); a[1] = f2bf(lo[1]);
    a[2] = f2bf(lo[2]); a[3] = f2bf(lo[3]);
    b[0] = f2bf(hi[0]); b[1] = f2bf(hi[1]);
    b[2] = f2bf(hi[2]); b[3] = f2bf(hi[3]);
    Bh[kt] = __builtin_shufflevector(a, b, 0, 1, 2, 3, 4, 5, 6, 7);
  }
  const float bhp0 = b_hp[0], bhp1 = b_hp[1];
  __syncthreads();

  // 7-trans nonlinearity for one 16-col chunk; returns 4 bf16 h values
  auto nonlin = [&](f32x4 (&acc)[4], f32x4& cr) -> bf16x4 {
    bf16x4 h4;
#pragma unroll
    for (int r = 0; r < 4; ++r) {
      float Q = 1.f + exp2_(-acc[0][r]);  // i
      float P = 1.f + exp2_(-acc[1][r]);  // f
      float R = 1.f + exp2_(-acc[2][r]);  // g
      float QR = Q * R;
      float rD = __builtin_amdgcn_rcpf(P * QR);
      float cn = (cr[r] * QR + (2.f - R) * P) * rD;
      cr[r] = cn;
      float T = 1.f + exp2_(cn * NEG2L);
      float S = 1.f + exp2_(-acc[3][r]);  // o
      h4[r] = f2bf((2.f - T) * __builtin_amdgcn_rcpf(S * T));
    }
    return h4;
  };
  // rel(t) = h(t+1) @ w_hp^T + b_hp; C col=ped, row=relcol -> lhi==0, r<2
  auto rel_do = [&](bf16x8 (&BhN)[4], int t) {
    f32x4 ar = {lhi == 0 ? bhp0 : 0.f, lhi == 0 ? bhp1 : 0.f, 0.f, 0.f};
#pragma unroll
    for (int kt = 0; kt < 4; ++kt) {
      bf16x8 wt = *(volatile const bf16x8*)&s_whp[kt * 512 + l * 8];
      ar = __builtin_amdgcn_mfma_f32_16x16x32_bf16(wt, BhN[kt], ar, 0, 0, 0);
    }
    if (lhi == 0) {
      f32x2 rv = {ar[0], ar[1]};
      *(f32x2*)&out[(size_t)t * (NPEDS * 2) + (size_t)ped * 2] = rv;
    }
  };

  // ---- transition 0: gates = w_hh*h0 + rank-2 lpr fold + b0eff ----
  {
    f32x2 lp = *(const f32x2*)&lpr[(size_t)ped * 2];
    bf16x8 BhN[4];
    bf16x4 loT;
#pragma unroll
    for (int c = 0; c < 8; ++c) {
      f32x4 acc[4];
#pragma unroll
      for (int g = 0; g < 4; ++g) {
        int n0 = g * HD + c * 16 + lhi * 4;
        f32x4 b0 = *(const f32x4*)&fl[512 + n0];
        f32x4 wa = *(const f32x4*)&fl[1024 + 2 * n0];
        f32x4 wb = *(const f32x4*)&fl[1024 + 2 * n0 + 4];
        f32x4 ci;
        ci[0] = b0[0] + wa[0] * lp[0] + wa[1] * lp[1];
        ci[1] = b0[1] + wa[2] * lp[0] + wa[3] * lp[1];
        ci[2] = b0[2] + wb[0] * lp[0] + wb[1] * lp[1];
        ci[3] = b0[3] + wb[2] * lp[0] + wb[3] * lp[1];
        bf16x8 Wf =
            *(volatile const bf16x8*)&s_w[((c * 4 + g) * 4 + 0) * 512 + l * 8];
        acc[g] =
            __builtin_amdgcn_mfma_f32_16x16x32_bf16(Wf, Bh[0], ci, 0, 0, 0);
      }
#pragma unroll
      for (int kt = 1; kt < 4; ++kt)
#pragma unroll
        for (int g = 0; g < 4; ++g) {
          bf16x8 Wf = *(volatile const bf16x8*)&s_w[((c * 4 + g) * 4 + kt) *
                                                        512 + l * 8];
          acc[g] = __builtin_amdgcn_mfma_f32_16x16x32_bf16(Wf, Bh[kt], acc[g],
                                                           0, 0, 0);
        }
      bf16x4 h4 = nonlin(acc, creg[c]);
      if (c & 1)
        BhN[c >> 1] = __builtin_shufflevector(loT, h4, 0, 1, 2, 3, 4, 5, 6, 7);
      else
        loT = h4;
    }
    rel_do(BhN, 0);
#pragma unroll
    for (int kt = 0; kt < 4; ++kt) Bh[kt] = BhN[kt];
  }
  __syncthreads();
  // restage s_w with W_eff fragments
  {
    const f32x4* src = (const f32x4*)(wsB + (size_t)WHH_FRAGS * 512);
    f32x4* dst = (f32x4*)s_w;
#pragma unroll
    for (int i = 0; i < 16; ++i) dst[i * 512 + tid] = src[i * 512 + tid];
  }
  __syncthreads();

  // ---- transitions 1..11: NO barriers; h/c in regs, weights from LDS ----
#pragma unroll 1
  for (int t = 1; t < SEQ; ++t) {
    bf16x8 BhN[4];
    bf16x4 loT;
#pragma unroll
    for (int c = 0; c < 8; ++c) {
      f32x4 acc[4];
#pragma unroll
      for (int g = 0; g < 4; ++g) {
        f32x4 ci = *(volatile const f32x4*)&s_beff[g * HD + c * 16 + lhi * 4];
        bf16x8 Wf =
            *(volatile const bf16x8*)&s_w[((c * 4 + g) * 4 + 0) * 512 + l * 8];
        acc[g] =
            __builtin_amdgcn_mfma_f32_16x16x32_bf16(Wf, Bh[0], ci, 0, 0, 0);
      }
#pragma unroll
      for (int kt = 1; kt < 4; ++kt)
#pragma unroll
        for (int g = 0; g < 4; ++g) {
          bf16x8 Wf = *(volatile const bf16x8*)&s_w[((c * 4 + g) * 4 + kt) *
                                                        512 + l * 8];
          acc[g] = __builtin_amdgcn_mfma_f32_16x16x32_bf16(Wf, Bh[kt], acc[g],
                                                           0, 0, 0);
        }
      bf16x4 h4 = nonlin(acc, creg[c]);
      if (c & 1)
        BhN[c >> 1] = __builtin_shufflevector(loT, h4, 0, 1, 2, 3, 4, 5, 6, 7);
      else
        loT = h4;
    }
    rel_do(BhN, t);
#pragma unroll
    for (int kt = 0; kt < 4; ++kt) Bh[kt] = BhN[kt];
  }
}

extern "C" void kernel_launch(void* const* d_in, const int* in_sizes, int n_in,
                              void* d_out, int out_size, void* d_ws,
                              size_t ws_size, hipStream_t stream) {
  // setup_inputs order:
  // 0 last_pos (unused), 1 last_pos_rel, 2 h0, 3 c0, 4 w_ih, 5 w_hh,
  // 6 b_ih, 7 b_hh, 8 w_se, 9 b_se, 10 w_hp, 11 b_hp
  const float* lpr = (const float*)d_in[1];
  const float* h0 = (const float*)d_in[2];
  const float* c0 = (const float*)d_in[3];
  const float* w_ih = (const float*)d_in[4];
  const float* w_hh = (const float*)d_in[5];
  const float* b_ih = (const float*)d_in[6];
  const float* b_hh = (const float*)d_in[7];
  const float* w_se = (const float*)d_in[8];
  const float* b_se = (const float*)d_in[9];
  const float* w_hp = (const float*)d_in[10];
  const float* b_hp = (const float*)d_in[11];
  short* wsB = (short*)d_ws;  // frags 266240 B + float tail 8192 B = 274432 B
  float* fl = (float*)((char*)d_ws + (size_t)NFRAGS * 512 * sizeof(short));
  float* out = (float*)d_out;

  prep_kernel<<<67, 256, 0, stream>>>(w_ih, w_hh, w_se, w_hp, b_ih, b_hh,
                                      b_se, b_hp, wsB, fl);
  lstm_kernel<<<NPEDS / MBLK, 512, 0, stream>>>(lpr, h0, c0, b_hp, wsB, fl,
                                                out);
}